// Round 1
// baseline (1687.538 us; speedup 1.0000x reference)
//
#include <hip/hip_runtime.h>
#include <math.h>

#define N_NODES 100000
#define N_EDGES 500000

__device__ __forceinline__ float gelu_f(float x) {
  // exact gelu: x * 0.5 * (1 + erf(x/sqrt(2)))
  return 0.5f * x * (1.0f + erff(x * 0.70710678118654752440f));
}

// ---------------- Kernel 1: per-node h = mlp(u,pn) + u@ipW + ipb ----------------
__global__ __launch_bounds__(256) void node_h_kernel(
    const float* __restrict__ node_u,
    const float* __restrict__ W1, const float* __restrict__ b1,
    const float* __restrict__ W2, const float* __restrict__ b2,
    const float* __restrict__ ipW, const float* __restrict__ ipb,
    float* __restrict__ h) {
  const int lane = threadIdx.x & 63;
  const int node = blockIdx.x * 4 + (threadIdx.x >> 6);
  if (node >= N_NODES) return;
  const float* u = node_u + (size_t)node * 5;
  const float u0 = u[0], u1 = u[1], u2 = u[2], u3 = u[3], u4 = u[4];
  float a = b1[lane];
  a = fmaf(u0, W1[0 * 64 + lane], a);
  a = fmaf(u1, W1[1 * 64 + lane], a);
  a = fmaf(u2, W1[2 * 64 + lane], a);
  a = fmaf(u3, W1[3 * 64 + lane], a);
  a = fmaf(u4, W1[4 * 64 + lane], a);
  const float g = gelu_f(a);
  float acc = b2[lane] + ipb[lane];
  acc = fmaf(u0, ipW[0 * 64 + lane], acc);
  acc = fmaf(u1, ipW[1 * 64 + lane], acc);
  acc = fmaf(u2, ipW[2 * 64 + lane], acc);
  acc = fmaf(u3, ipW[3 * 64 + lane], acc);
  acc = fmaf(u4, ipW[4 * 64 + lane], acc);
  for (int k = 0; k < 64; ++k) {
    acc = fmaf(__shfl(g, k, 64), W2[k * 64 + lane], acc);
  }
  h[(size_t)node * 64 + lane] = acc;
}

// ---------------- Kernel 2: per-edge fused pipeline, 32 edges / block ----------------
struct EdgeArgs {
  const float *node_u, *edge_attr, *mean_mom, *std_mom, *edge_mem;
  const int* eidx;
  const float *pe_W1, *pe_b1, *pe_W2, *pe_b2;
  const float *pm_W1, *pm_b1, *pm_W2, *pm_b2;
  const float *prho_W1, *prho_b1, *prho_W2, *prho_b2;
  const float *pen_W1, *pen_b1, *pen_W2, *pen_b2;
  const float *pmu_W1, *pmu_b1, *pmu_W2, *pmu_b2;
  const float *pv_W1, *pv_b1, *pv_W2, *pv_b2;
  const float *ln_g, *ln_b;
  const float* h;
  float* out;
};

#define SA_STR 296   // msg_in row stride (292 padded to mult of 4)
#define ZS 225       // z (head hidden) row stride

__global__ __launch_bounds__(256, 2) void edge_kernel(EdgeArgs A) {
  __shared__ __align__(16) float sA[32 * SA_STR];   // msg_in; later overlaid by z
  __shared__ __align__(16) float sH1[32 * 128];     // layer1 out; early: eps1 overlay
  __shared__ __align__(16) float sM[32 * 64];       // m (pre/post LN)
  __shared__ float sStash[32 * 8];                  // n0,n1,r,du0,du1,du3,du4
  __shared__ int sIdx[64];                          // src[32], dst[32]
  float* sE1 = sH1;   // eps hidden overlay (used only before sH1 written)
  float* sZ = sA;     // head-hidden overlay (used only after sA dead)

  const int tid = threadIdx.x;
  const int e0 = blockIdx.x * 32;

  // ---- E1a: per-edge scalars (vel_proj, n, t, du, indices)
  if (tid < 32) {
    const int e = e0 + tid;
    const int s = A.eidx[e];
    const int d = A.eidx[N_EDGES + e];
    sIdx[tid] = s;
    sIdx[32 + tid] = d;
    const float dx = A.edge_attr[e * 3 + 0];
    const float dy = A.edge_attr[e * 3 + 1];
    const float r = A.edge_attr[e * 3 + 2];
    const float inv = 1.0f / (r + 1e-12f);
    const float n0 = dx * inv, n1 = dy * inv;  // t = (-n1, n0)
    const float* us = A.node_u + (size_t)s * 5;
    const float* ud = A.node_u + (size_t)d * 5;
    const float sm0 = A.std_mom[0], sm1 = A.std_mom[1];
    const float mm0 = A.mean_mom[0], mm1 = A.mean_mom[1];
    const float rs0 = fmaf(us[3], sm0, mm0), rs1 = fmaf(us[4], sm1, mm1);
    const float rd0 = fmaf(ud[3], sm0, mm0), rd1 = fmaf(ud[4], sm1, mm1);
    const float isc = 1.0f / (sqrtf(sm0 * sm0 + sm1 * sm1) + 1e-8f);
    float* row = &sA[tid * SA_STR];
    row[288] = (rs0 * n0 + rs1 * n1) * isc;
    row[289] = (-rs0 * n1 + rs1 * n0) * isc;
    row[290] = (rd0 * n0 + rd1 * n1) * isc;
    row[291] = (-rd0 * n1 + rd1 * n0) * isc;
    float* st = &sStash[tid * 8];
    st[0] = n0; st[1] = n1; st[2] = r;
    st[3] = ud[0] - us[0];
    st[4] = ud[1] - us[1];
    st[5] = ud[3] - us[3];
    st[6] = ud[4] - us[4];
  }
  __syncthreads();

  // ---- E1b-1: eps hidden (1 -> 32, gelu)
  {
    const int i = tid & 31, eg = tid >> 5;
    const float w = A.pe_W1[i], b = A.pe_b1[i];
#pragma unroll
    for (int p = 0; p < 4; ++p) {
      const int e = p * 8 + eg;
      sE1[e * 33 + i] = gelu_f(fmaf(sStash[e * 8 + 2], w, b));
    }
  }
  __syncthreads();

  // ---- E1b-2: eps out (32 -> 32) into msg_in[256..287]
  {
    const int i = tid & 31, eg = tid >> 5;
#pragma unroll
    for (int p = 0; p < 4; ++p) {
      const int e = p * 8 + eg;
      float acc = A.pe_b2[i];
      for (int k = 0; k < 32; ++k) acc = fmaf(sE1[e * 33 + k], A.pe_W2[k * 32 + i], acc);
      sA[e * SA_STR + 256 + i] = acc;
    }
  }
  // ---- E1c: h gathers into msg_in[0..255] (disjoint from E1b-2 writes)
  {
    const int f = tid & 63, es = tid >> 6;
#pragma unroll
    for (int p = 0; p < 8; ++p) {
      const int e = p * 4 + es;
      const float hs = A.h[(size_t)sIdx[e] * 64 + f];
      const float hd = A.h[(size_t)sIdx[32 + e] * 64 + f];
      float* row = &sA[e * SA_STR];
      row[f] = hs;
      row[64 + f] = hd;
      row[128 + f] = hs + hd;
      const float dv = hs - hd;
      row[192 + f] = dv * dv;
    }
  }
  __syncthreads();

  // ---- E2: layer1 (292 -> 128, gelu). thread = (jj in 0..127, eg in 0..1), 16 edges each
  {
    const int jj = tid & 127, eg = tid >> 7;
    const float bv = A.pm_b1[jj];
    float acc[16];
#pragma unroll
    for (int i = 0; i < 16; ++i) acc[i] = bv;
    const float* srow = &sA[eg * 16 * SA_STR];
    for (int k = 0; k < 292; k += 4) {
      const float w0 = A.pm_W1[(k + 0) * 128 + jj];
      const float w1 = A.pm_W1[(k + 1) * 128 + jj];
      const float w2 = A.pm_W1[(k + 2) * 128 + jj];
      const float w3 = A.pm_W1[(k + 3) * 128 + jj];
#pragma unroll
      for (int i = 0; i < 16; ++i) {
        const float4 a4 = *(const float4*)&srow[i * SA_STR + k];
        acc[i] = fmaf(a4.x, w0, acc[i]);
        acc[i] = fmaf(a4.y, w1, acc[i]);
        acc[i] = fmaf(a4.z, w2, acc[i]);
        acc[i] = fmaf(a4.w, w3, acc[i]);
      }
    }
#pragma unroll
    for (int i = 0; i < 16; ++i) sH1[(eg * 16 + i) * 128 + jj] = gelu_f(acc[i]);
  }
  __syncthreads();

  // ---- E3: layer2 (128 -> 64) + edge_memory add
  {
    const int j = tid & 63, eg = tid >> 6;
    const float bv = A.pm_b2[j];
    float acc[8];
#pragma unroll
    for (int i = 0; i < 8; ++i) acc[i] = bv;
    const float* hrow = &sH1[eg * 8 * 128];
    for (int k = 0; k < 128; k += 4) {
      const float w0 = A.pm_W2[(k + 0) * 64 + j];
      const float w1 = A.pm_W2[(k + 1) * 64 + j];
      const float w2 = A.pm_W2[(k + 2) * 64 + j];
      const float w3 = A.pm_W2[(k + 3) * 64 + j];
#pragma unroll
      for (int i = 0; i < 8; ++i) {
        const float4 a4 = *(const float4*)&hrow[i * 128 + k];
        acc[i] = fmaf(a4.x, w0, acc[i]);
        acc[i] = fmaf(a4.y, w1, acc[i]);
        acc[i] = fmaf(a4.z, w2, acc[i]);
        acc[i] = fmaf(a4.w, w3, acc[i]);
      }
    }
#pragma unroll
    for (int i = 0; i < 8; ++i) {
      const int e = eg * 8 + i;
      sM[e * 64 + j] = acc[i] + A.edge_mem[(size_t)(e0 + e) * 64 + j];
    }
  }
  __syncthreads();

  // ---- LN: wave-shuffle layernorm per edge row, also writes m output
  {
    const int f = tid & 63, w = tid >> 6;
    const float g = A.ln_g[f], b = A.ln_b[f];
    float* out_m = A.out + (size_t)10 * N_EDGES;
#pragma unroll
    for (int p = 0; p < 8; ++p) {
      const int e = p * 4 + w;
      const float x = sM[e * 64 + f];
      float s = x, s2 = x * x;
#pragma unroll
      for (int off = 32; off > 0; off >>= 1) {
        s += __shfl_xor(s, off, 64);
        s2 += __shfl_xor(s2, off, 64);
      }
      const float mean = s * (1.0f / 64.0f);
      const float var = fmaxf(s2 * (1.0f / 64.0f) - mean * mean, 0.0f);
      const float rstd = rsqrtf(var + 1e-5f);
      const float y = fmaf((x - mean) * rstd, g, b);
      sM[e * 64 + f] = y;
      out_m[(size_t)(e0 + e) * 64 + f] = y;
    }
  }
  __syncthreads();

  // ---- E4: head hidden layers (m -> 224 hidden units, gelu), z overlays sA
  {
    const int u = tid & 31, eg = tid >> 5;
#pragma unroll
    for (int half = 0; half < 2; ++half) {
      const int unit = half * 32 + u;
      float a0[4], a1[4], a2[4];
      const float b0 = A.prho_b1[unit], b1v = A.pen_b1[unit], b2v = A.pmu_b1[unit];
#pragma unroll
      for (int p = 0; p < 4; ++p) { a0[p] = b0; a1[p] = b1v; a2[p] = b2v; }
      for (int k = 0; k < 64; ++k) {
        const float w0 = A.prho_W1[k * 64 + unit];
        const float w1 = A.pen_W1[k * 64 + unit];
        const float w2 = A.pmu_W1[k * 64 + unit];
#pragma unroll
        for (int p = 0; p < 4; ++p) {
          const float mv = sM[(p * 8 + eg) * 64 + k];
          a0[p] = fmaf(mv, w0, a0[p]);
          a1[p] = fmaf(mv, w1, a1[p]);
          a2[p] = fmaf(mv, w2, a2[p]);
        }
      }
#pragma unroll
      for (int p = 0; p < 4; ++p) {
        const int e = p * 8 + eg;
        sZ[e * ZS + unit] = gelu_f(a0[p]);
        sZ[e * ZS + 64 + unit] = gelu_f(a1[p]);
        sZ[e * ZS + 128 + unit] = gelu_f(a2[p]);
      }
    }
    {  // v head (32 hidden)
      const float bv = A.pv_b1[u];
      float a[4];
#pragma unroll
      for (int p = 0; p < 4; ++p) a[p] = bv;
      for (int k = 0; k < 64; ++k) {
        const float w = A.pv_W1[k * 32 + u];
#pragma unroll
        for (int p = 0; p < 4; ++p) a[p] = fmaf(sM[(p * 8 + eg) * 64 + k], w, a[p]);
      }
#pragma unroll
      for (int p = 0; p < 4; ++p) sZ[(p * 8 + eg) * ZS + 192 + u] = gelu_f(a[p]);
    }
  }
  __syncthreads();

  // ---- E5: head outputs + flux epilogue
  if (tid < 32) {
    const int e = tid;
    const float* z = &sZ[e * ZS];
    float arho = A.prho_b2[0], aen = A.pen_b2[0];
    float amu0 = A.pmu_b2[0], amu1 = A.pmu_b2[1];
    float av = A.pv_b2[0];
    for (int k = 0; k < 64; ++k) {
      arho = fmaf(z[k], A.prho_W2[k], arho);
      aen = fmaf(z[64 + k], A.pen_W2[k], aen);
      const float zm = z[128 + k];
      amu0 = fmaf(zm, A.pmu_W2[k * 2 + 0], amu0);
      amu1 = fmaf(zm, A.pmu_W2[k * 2 + 1], amu1);
    }
    for (int k = 0; k < 32; ++k) av = fmaf(z[192 + k], A.pv_W2[k], av);
    const float alpha = 1.0f / (1.0f + expf(-av));
    const float* st = &sStash[e * 8];
    const float n0 = st[0], n1 = st[1], r = st[2];
    const float du0 = st[3], du1 = st[4], du3 = st[5], du4 = st[6];
    const size_t ge = (size_t)(e0 + e);
    float* out = A.out;
    const float c0 = arho - alpha * du0;   // F_rho = (a_rho - alpha*du0) * n
    out[ge * 2 + 0] = c0 * n0;
    out[ge * 2 + 1] = c0 * n1;
    const float c1 = aen - alpha * du1;    // F_e = (a_e - alpha*du1) * n
    out[(size_t)2 * N_EDGES + ge * 2 + 0] = c1 * n0;
    out[(size_t)2 * N_EDGES + ge * 2 + 1] = c1 * n1;
    // F_rhou = mu0*n + mu1*t - alpha*du[3:5], t = (-n1, n0)
    out[(size_t)4 * N_EDGES + ge * 2 + 0] = amu0 * n0 - amu1 * n1 - alpha * du3;
    out[(size_t)4 * N_EDGES + ge * 2 + 1] = amu0 * n1 + amu1 * n0 - alpha * du4;
    out[(size_t)6 * N_EDGES + ge * 2 + 0] = n0;
    out[(size_t)6 * N_EDGES + ge * 2 + 1] = n1;
    out[(size_t)8 * N_EDGES + ge] = r;
    out[(size_t)9 * N_EDGES + ge] = alpha;
  }
}

extern "C" void kernel_launch(void* const* d_in, const int* in_sizes, int n_in,
                              void* d_out, int out_size, void* d_ws, size_t ws_size,
                              hipStream_t stream) {
  const float* node_u = (const float*)d_in[0];
  const float* edge_attr = (const float*)d_in[1];
  const float* mean_mom = (const float*)d_in[2];
  const float* std_mom = (const float*)d_in[3];
  const float* edge_mem = (const float*)d_in[4];
  const int* eidx = (const int*)d_in[5];
  const float* pn_W1 = (const float*)d_in[6];
  const float* pn_b1 = (const float*)d_in[7];
  const float* pn_W2 = (const float*)d_in[8];
  const float* pn_b2 = (const float*)d_in[9];
  const float* ip_W = (const float*)d_in[10];
  const float* ip_b = (const float*)d_in[11];

  EdgeArgs A;
  A.node_u = node_u;
  A.edge_attr = edge_attr;
  A.mean_mom = mean_mom;
  A.std_mom = std_mom;
  A.edge_mem = edge_mem;
  A.eidx = eidx;
  A.pe_W1 = (const float*)d_in[12];
  A.pe_b1 = (const float*)d_in[13];
  A.pe_W2 = (const float*)d_in[14];
  A.pe_b2 = (const float*)d_in[15];
  A.pm_W1 = (const float*)d_in[16];
  A.pm_b1 = (const float*)d_in[17];
  A.pm_W2 = (const float*)d_in[18];
  A.pm_b2 = (const float*)d_in[19];
  A.prho_W1 = (const float*)d_in[20];
  A.prho_b1 = (const float*)d_in[21];
  A.prho_W2 = (const float*)d_in[22];
  A.prho_b2 = (const float*)d_in[23];
  A.pen_W1 = (const float*)d_in[24];
  A.pen_b1 = (const float*)d_in[25];
  A.pen_W2 = (const float*)d_in[26];
  A.pen_b2 = (const float*)d_in[27];
  A.pmu_W1 = (const float*)d_in[28];
  A.pmu_b1 = (const float*)d_in[29];
  A.pmu_W2 = (const float*)d_in[30];
  A.pmu_b2 = (const float*)d_in[31];
  A.pv_W1 = (const float*)d_in[32];
  A.pv_b1 = (const float*)d_in[33];
  A.pv_W2 = (const float*)d_in[34];
  A.pv_b2 = (const float*)d_in[35];
  A.ln_g = (const float*)d_in[36];
  A.ln_b = (const float*)d_in[37];
  A.h = (const float*)d_ws;   // N_NODES*64 floats = 25.6 MB scratch
  A.out = (float*)d_out;

  node_h_kernel<<<N_NODES / 4, 256, 0, stream>>>(node_u, pn_W1, pn_b1, pn_W2, pn_b2,
                                                 ip_W, ip_b, (float*)d_ws);
  edge_kernel<<<N_EDGES / 32, 256, 0, stream>>>(A);
}

// Round 2
// 520.416 us; speedup vs baseline: 3.2427x; 3.2427x over previous
//
#include <hip/hip_runtime.h>
#include <math.h>

#define NN 100000
#define NE 500000

typedef short bf16x8 __attribute__((ext_vector_type(8)));
typedef float f32x4 __attribute__((ext_vector_type(4)));

__device__ __forceinline__ float gelu_f(float x) {
  return 0.5f * x * (1.0f + erff(x * 0.70710678118654752440f));
}
__device__ __forceinline__ short f2bf(float x) {  // RNE float->bf16
  unsigned u = __builtin_bit_cast(unsigned, x);
  u = (u + 0x7FFFu + ((u >> 16) & 1u)) >> 16;
  return (short)u;
}
__device__ __forceinline__ float bf2f(short s) {
  unsigned u = ((unsigned)(unsigned short)s) << 16;
  return __builtin_bit_cast(float, u);
}
__device__ __forceinline__ unsigned pack2(float a, float b) {
  return (unsigned)(unsigned short)f2bf(a) | (((unsigned)(unsigned short)f2bf(b)) << 16);
}

// ---------------- Kernel 1: per-node h = mlp(u,pn) + u@ipW + ipb (f32) ----------------
__global__ __launch_bounds__(256) void node_h_kernel(
    const float* __restrict__ node_u,
    const float* __restrict__ W1, const float* __restrict__ b1,
    const float* __restrict__ W2, const float* __restrict__ b2,
    const float* __restrict__ ipW, const float* __restrict__ ipb,
    float* __restrict__ h) {
  const int lane = threadIdx.x & 63;
  const int node = blockIdx.x * 4 + (threadIdx.x >> 6);
  if (node >= NN) return;
  const float* u = node_u + (size_t)node * 5;
  const float u0 = u[0], u1 = u[1], u2 = u[2], u3 = u[3], u4 = u[4];
  float a = b1[lane];
  a = fmaf(u0, W1[0 * 64 + lane], a);
  a = fmaf(u1, W1[1 * 64 + lane], a);
  a = fmaf(u2, W1[2 * 64 + lane], a);
  a = fmaf(u3, W1[3 * 64 + lane], a);
  a = fmaf(u4, W1[4 * 64 + lane], a);
  const float g = gelu_f(a);
  float acc = b2[lane] + ipb[lane];
  acc = fmaf(u0, ipW[0 * 64 + lane], acc);
  acc = fmaf(u1, ipW[1 * 64 + lane], acc);
  acc = fmaf(u2, ipW[2 * 64 + lane], acc);
  acc = fmaf(u3, ipW[3 * 64 + lane], acc);
  acc = fmaf(u4, ipW[4 * 64 + lane], acc);
  for (int k = 0; k < 64; ++k) {
    acc = fmaf(__shfl(g, k, 64), W2[k * 64 + lane], acc);
  }
  h[(size_t)node * 64 + lane] = acc;
}

// ---------------- Kernel 0: repack GEMM weights to bf16 fragment order ----------------
// Fragment block = 512 bf16: lane l (0..63) x elem e (0..7); value = W[k][n],
// k = ks*32 + 8*(l>>4) + e, n = nt*16 + (l&15).  (A-side uses the same k map.)
__global__ __launch_bounds__(256) void prep_kernel(
    const float* __restrict__ pm_W1, const float* __restrict__ pm_W2,
    const float* __restrict__ prho_W1, const float* __restrict__ pen_W1,
    const float* __restrict__ pmu_W1, const float* __restrict__ pv_W1,
    const float* __restrict__ prho_b1, const float* __restrict__ pen_b1,
    const float* __restrict__ pmu_b1, const float* __restrict__ pv_b1,
    short* __restrict__ W1P, short* __restrict__ W2P, short* __restrict__ WHP,
    float* __restrict__ HB) {
  int t = blockIdx.x * 256 + threadIdx.x;
  if (t < 40960) {  // pm_W1: 292(->320)x128, [nt=8][ks=10][512]
    const int nt = t / 5120, rem = t % 5120;
    const int ks = rem / 512, li = rem % 512;
    const int l = li >> 3, e = li & 7;
    const int k = ks * 32 + ((l >> 4) << 3) + e;
    const int n = nt * 16 + (l & 15);
    W1P[t] = (k < 292) ? f2bf(pm_W1[k * 128 + n]) : (short)0;
    return;
  }
  t -= 40960;
  if (t < 8192) {  // pm_W2: 128x64, [nt=4][ks=4][512]
    const int nt = t / 2048, rem = t % 2048;
    const int ks = rem / 512, li = rem % 512;
    const int l = li >> 3, e = li & 7;
    const int k = ks * 32 + ((l >> 4) << 3) + e;
    const int n = nt * 16 + (l & 15);
    W2P[t] = f2bf(pm_W2[k * 64 + n]);
    return;
  }
  t -= 8192;
  if (t < 14336) {  // heads W1 concat: 64x224, [nt=14][ks=2][512]
    const int nt = t / 1024, rem = t % 1024;
    const int ks = rem / 512, li = rem % 512;
    const int l = li >> 3, e = li & 7;
    const int k = ks * 32 + ((l >> 4) << 3) + e;
    const int col = nt * 16 + (l & 15);
    float v;
    if (col < 64) v = prho_W1[k * 64 + col];
    else if (col < 128) v = pen_W1[k * 64 + (col - 64)];
    else if (col < 192) v = pmu_W1[k * 64 + (col - 128)];
    else v = pv_W1[k * 32 + (col - 192)];
    WHP[t] = f2bf(v);
    return;
  }
  t -= 14336;
  if (t < 224) {  // head biases concat (f32)
    HB[t] = (t < 64) ? prho_b1[t]
          : (t < 128) ? pen_b1[t - 64]
          : (t < 192) ? pmu_b1[t - 128]
          : pv_b1[t - 192];
  }
}

// ---------------- Kernel 2: per-edge fused MFMA pipeline, 32 edges / block ----------------
struct EdgeArgs {
  const float *node_u, *edge_attr, *mean_mom, *std_mom, *edge_mem;
  const int* eidx;
  const float *pe_W1, *pe_b1, *pe_W2, *pe_b2;
  const float *pm_b1, *pm_b2;
  const float *prho_W2, *prho_b2;
  const float *pen_W2, *pen_b2;
  const float *pmu_W2, *pmu_b2;
  const float *pv_W2, *pv_b2;
  const float *ln_g, *ln_b;
  const float* h;
  const short *W1P, *W2P, *WHP;
  const float* HB;
  float* out;
};

#define SMS 328   // msg bf16 row stride (656 B; 656/4 % 32 == 4 -> 2-way free)
#define H1S 136   // h1 bf16 row stride (272 B)
#define MSR 72    // m bf16 row stride (144 B)
#define ZST 233   // z bf16 row stride (466 B)
#define MPS 68    // m_pre f32 row stride

#define OFF_A   0       // 20992 B: msg bf16 [32][328]; then m_pre f32 [32][68]; then z bf16 [32][233]
#define OFF_H1  20992   // 8704 B: h1 bf16 [32][136]; early: eps hidden f32 [32][33]
#define OFF_M   29696   // 4608 B: m bf16 [32][72]
#define OFF_SC  34304   // 1024 B: per-edge stash f32 [32][8]
#define OFF_SC2 35328   // 1024 B: head results f32 [32][8]
#define OFF_IDX 36352   // 256 B: src[32], dst[32]
#define SMEM_BYTES 36608

#define MFMA16(a, b, c) __builtin_amdgcn_mfma_f32_16x16x32_bf16((a), (b), (c), 0, 0, 0)

__global__ __launch_bounds__(256, 4) void edge_kernel(EdgeArgs A) {
  __shared__ __align__(16) char smem[SMEM_BYTES];
  short* aA = (short*)(smem + OFF_A);
  short* aH1 = (short*)(smem + OFF_H1);
  float* sEps = (float*)(smem + OFF_H1);
  short* aM = (short*)(smem + OFF_M);
  float* mPre = (float*)(smem + OFF_A);
  short* aZ = (short*)(smem + OFF_A);
  float* sSc = (float*)(smem + OFF_SC);
  float* sSc2 = (float*)(smem + OFF_SC2);
  int* sIdx = (int*)(smem + OFF_IDX);

  const int tid = threadIdx.x;
  const int e0 = blockIdx.x * 32;
  const int lane = tid & 63;
  const int wv = tid >> 6;
  const int l15 = lane & 15, g = lane >> 4;
  const int mt = wv & 1, nh = wv >> 1;

  // ---- S0a: per-edge scalars (vel_proj, n, t, du, indices) + zero K-pad
  if (tid < 32) {
    const int e = e0 + tid;
    const int s = A.eidx[e];
    const int d = A.eidx[NE + e];
    sIdx[tid] = s;
    sIdx[32 + tid] = d;
    const float dx = A.edge_attr[e * 3 + 0];
    const float dy = A.edge_attr[e * 3 + 1];
    const float r = A.edge_attr[e * 3 + 2];
    const float inv = 1.0f / (r + 1e-12f);
    const float n0 = dx * inv, n1 = dy * inv;  // t = (-n1, n0)
    const float* us = A.node_u + (size_t)s * 5;
    const float* ud = A.node_u + (size_t)d * 5;
    const float sm0 = A.std_mom[0], sm1 = A.std_mom[1];
    const float mm0 = A.mean_mom[0], mm1 = A.mean_mom[1];
    const float rs0 = fmaf(us[3], sm0, mm0), rs1 = fmaf(us[4], sm1, mm1);
    const float rd0 = fmaf(ud[3], sm0, mm0), rd1 = fmaf(ud[4], sm1, mm1);
    const float isc = 1.0f / (sqrtf(sm0 * sm0 + sm1 * sm1) + 1e-8f);
    short* mrow = aA + tid * SMS;
    mrow[288] = f2bf((rs0 * n0 + rs1 * n1) * isc);
    mrow[289] = f2bf((-rs0 * n1 + rs1 * n0) * isc);
    mrow[290] = f2bf((rd0 * n0 + rd1 * n1) * isc);
    mrow[291] = f2bf((-rd0 * n1 + rd1 * n0) * isc);
    unsigned* zp = (unsigned*)(mrow + 292);  // byte offset 584, 4-aligned
#pragma unroll
    for (int z = 0; z < 14; ++z) zp[z] = 0u;  // zero K-pad cols 292..319
    float* st = &sSc[tid * 8];
    st[0] = n0; st[1] = n1; st[2] = r;
    st[3] = ud[0] - us[0];
    st[4] = ud[1] - us[1];
    st[5] = ud[3] - us[3];
    st[6] = ud[4] - us[4];
  }
  __syncthreads();

  // ---- S0b: eps hidden (1 -> 32, gelu), f32 in sEps (overlay on h1 buffer)
  {
    const int i = tid & 31, eg = tid >> 5;
    const float w1 = A.pe_W1[i], b1 = A.pe_b1[i];
#pragma unroll
    for (int p = 0; p < 4; ++p) {
      const int el = eg * 4 + p;
      sEps[el * 33 + i] = gelu_f(fmaf(sSc[el * 8 + 2], w1, b1));
    }
  }
  __syncthreads();

  // ---- S0c: eps out (32 -> 32) -> msg cols [256..288) bf16
  {
    const int i = tid & 31, eg = tid >> 5;
#pragma unroll
    for (int p = 0; p < 4; ++p) {
      const int el = eg * 4 + p;
      float acc = A.pe_b2[i];
      for (int k = 0; k < 32; ++k) acc = fmaf(sEps[el * 33 + k], A.pe_W2[k * 32 + i], acc);
      aA[el * SMS + 256 + i] = f2bf(acc);
    }
  }
  // ---- S0d: h gathers -> msg cols [0..256) bf16 (packed b32 writes)
  {
    const int c = tid & 31, eg = tid >> 5;
#pragma unroll
    for (int p = 0; p < 4; ++p) {
      const int el = eg * 4 + p;
      const float2 hs = *(const float2*)&A.h[(size_t)sIdx[el] * 64 + 2 * c];
      const float2 hd = *(const float2*)&A.h[(size_t)sIdx[32 + el] * 64 + 2 * c];
      unsigned* rp = (unsigned*)((char*)aA + el * (SMS * 2));
      rp[c] = pack2(hs.x, hs.y);
      rp[32 + c] = pack2(hd.x, hd.y);
      rp[64 + c] = pack2(hs.x + hd.x, hs.y + hd.y);
      const float d0 = hs.x - hd.x, d1 = hs.y - hd.y;
      rp[96 + c] = pack2(d0 * d0, d1 * d1);
    }
  }
  __syncthreads();

  // ---- E2: layer1 MFMA (K=320 incl pad, N=128). wave (mt,nh): rows 16mt.., cols 64nh..
  {
    const char* arow = (const char*)aA + (mt * 16 + l15) * (SMS * 2) + g * 16;
    const short* BW = A.W1P + nh * 4 * 10 * 512 + lane * 8;
    f32x4 ac0 = {0.f, 0.f, 0.f, 0.f}, ac1 = ac0, ac2 = ac0, ac3 = ac0;
    for (int ks = 0; ks < 10; ++ks) {
      const bf16x8 a = *(const bf16x8*)(arow + ks * 64);
      const bf16x8 b0 = *(const bf16x8*)(BW + (0 * 10 + ks) * 512);
      const bf16x8 b1 = *(const bf16x8*)(BW + (1 * 10 + ks) * 512);
      const bf16x8 b2 = *(const bf16x8*)(BW + (2 * 10 + ks) * 512);
      const bf16x8 b3 = *(const bf16x8*)(BW + (3 * 10 + ks) * 512);
      ac0 = MFMA16(a, b0, ac0);
      ac1 = MFMA16(a, b1, ac1);
      ac2 = MFMA16(a, b2, ac2);
      ac3 = MFMA16(a, b3, ac3);
    }
    const int rb = mt * 16 + g * 4;
#define EPI1(j, accv) { \
    const int col = (nh * 4 + (j)) * 16 + l15; \
    const float bb = A.pm_b1[col]; \
    _Pragma("unroll") \
    for (int rg = 0; rg < 4; ++rg) \
      aH1[(rb + rg) * H1S + col] = f2bf(gelu_f(accv[rg] + bb)); \
  }
    EPI1(0, ac0) EPI1(1, ac1) EPI1(2, ac2) EPI1(3, ac3)
#undef EPI1
  }
  __syncthreads();

  // ---- E3: layer2 MFMA (K=128, N=64) + bias + edge_memory -> m_pre f32 (overlay aA)
  {
    const char* arow = (const char*)aH1 + (mt * 16 + l15) * (H1S * 2) + g * 16;
    const short* BW = A.W2P + nh * 2 * 4 * 512 + lane * 8;
    f32x4 ac0 = {0.f, 0.f, 0.f, 0.f}, ac1 = ac0;
    for (int ks = 0; ks < 4; ++ks) {
      const bf16x8 a = *(const bf16x8*)(arow + ks * 64);
      const bf16x8 b0 = *(const bf16x8*)(BW + (0 * 4 + ks) * 512);
      const bf16x8 b1 = *(const bf16x8*)(BW + (1 * 4 + ks) * 512);
      ac0 = MFMA16(a, b0, ac0);
      ac1 = MFMA16(a, b1, ac1);
    }
    const int rb = mt * 16 + g * 4;
#define EPI2(j, accv) { \
    const int col = (nh * 2 + (j)) * 16 + l15; \
    const float bb = A.pm_b2[col]; \
    _Pragma("unroll") \
    for (int rg = 0; rg < 4; ++rg) { \
      const int row = rb + rg; \
      mPre[row * MPS + col] = accv[rg] + bb + A.edge_mem[(size_t)(e0 + row) * 64 + col]; \
    } \
  }
    EPI2(0, ac0) EPI2(1, ac1)
#undef EPI2
  }
  __syncthreads();

  // ---- LN: shuffle layernorm per edge row; writes m bf16 (aM) + m f32 (global out)
  {
    const float lg = A.ln_g[lane], lb = A.ln_b[lane];
    float* out_m = A.out + (size_t)10 * NE;
#pragma unroll
    for (int p = 0; p < 8; ++p) {
      const int r = p * 4 + wv;
      const float x = mPre[r * MPS + lane];
      float s = x, s2 = x * x;
#pragma unroll
      for (int off = 32; off > 0; off >>= 1) {
        s += __shfl_xor(s, off, 64);
        s2 += __shfl_xor(s2, off, 64);
      }
      const float mean = s * (1.0f / 64.0f);
      const float var = fmaxf(s2 * (1.0f / 64.0f) - mean * mean, 0.0f);
      const float rstd = rsqrtf(var + 1e-5f);
      const float y = fmaf((x - mean) * rstd, lg, lb);
      aM[r * MSR + lane] = f2bf(y);
      out_m[(size_t)(e0 + r) * 64 + lane] = y;
    }
  }
  __syncthreads();

  // ---- E4: head hidden MFMA (K=64, N=224), gelu -> z bf16 (overlay aA)
  {
    const char* arow = (const char*)aM + (mt * 16 + l15) * (MSR * 2) + g * 16;
    const bf16x8 a0 = *(const bf16x8*)(arow);
    const bf16x8 a1 = *(const bf16x8*)(arow + 64);
    const short* BW = A.WHP + nh * 7 * 2 * 512 + lane * 8;
    const int rb = mt * 16 + g * 4;
#define HEADJ(j) { \
    f32x4 acc = {0.f, 0.f, 0.f, 0.f}; \
    acc = MFMA16(a0, *(const bf16x8*)(BW + ((j) * 2 + 0) * 512), acc); \
    acc = MFMA16(a1, *(const bf16x8*)(BW + ((j) * 2 + 1) * 512), acc); \
    const int col = (nh * 7 + (j)) * 16 + l15; \
    const float bb = A.HB[col]; \
    _Pragma("unroll") \
    for (int rg = 0; rg < 4; ++rg) \
      aZ[(rb + rg) * ZST + col] = f2bf(gelu_f(acc[rg] + bb)); \
  }
    HEADJ(0) HEADJ(1) HEADJ(2) HEADJ(3) HEADJ(4) HEADJ(5) HEADJ(6)
#undef HEADJ
  }
  __syncthreads();

  // ---- E5: head output dots (thread = edge x head)
  if (tid < 128) {
    const int e = tid & 31, hd = tid >> 5;
    const short* z = aZ + e * ZST;
    if (hd == 0) {
      float a = A.prho_b2[0];
      for (int k = 0; k < 64; ++k) a = fmaf(bf2f(z[k]), A.prho_W2[k], a);
      sSc2[e * 8 + 0] = a;
    } else if (hd == 1) {
      float a = A.pen_b2[0];
      for (int k = 0; k < 64; ++k) a = fmaf(bf2f(z[64 + k]), A.pen_W2[k], a);
      sSc2[e * 8 + 1] = a;
    } else if (hd == 2) {
      float a0 = A.pmu_b2[0], a1 = A.pmu_b2[1];
      for (int k = 0; k < 64; ++k) {
        const float zv = bf2f(z[128 + k]);
        a0 = fmaf(zv, A.pmu_W2[k * 2 + 0], a0);
        a1 = fmaf(zv, A.pmu_W2[k * 2 + 1], a1);
      }
      sSc2[e * 8 + 2] = a0;
      sSc2[e * 8 + 3] = a1;
    } else {
      float a = A.pv_b2[0];
      for (int k = 0; k < 32; ++k) a = fmaf(bf2f(z[192 + k]), A.pv_W2[k], a);
      sSc2[e * 8 + 4] = 1.0f / (1.0f + expf(-a));
    }
  }
  __syncthreads();

  // ---- E5b: flux epilogue
  if (tid < 32) {
    const int e = tid;
    const float* st = &sSc[e * 8];
    const float n0 = st[0], n1 = st[1], r = st[2];
    const float du0 = st[3], du1 = st[4], du3 = st[5], du4 = st[6];
    const float arho = sSc2[e * 8 + 0], aen = sSc2[e * 8 + 1];
    const float amu0 = sSc2[e * 8 + 2], amu1 = sSc2[e * 8 + 3];
    const float alpha = sSc2[e * 8 + 4];
    const size_t ge = (size_t)(e0 + e);
    float* out = A.out;
    const float c0 = arho - alpha * du0;
    out[ge * 2 + 0] = c0 * n0;
    out[ge * 2 + 1] = c0 * n1;
    const float c1 = aen - alpha * du1;
    out[(size_t)2 * NE + ge * 2 + 0] = c1 * n0;
    out[(size_t)2 * NE + ge * 2 + 1] = c1 * n1;
    out[(size_t)4 * NE + ge * 2 + 0] = amu0 * n0 - amu1 * n1 - alpha * du3;
    out[(size_t)4 * NE + ge * 2 + 1] = amu0 * n1 + amu1 * n0 - alpha * du4;
    out[(size_t)6 * NE + ge * 2 + 0] = n0;
    out[(size_t)6 * NE + ge * 2 + 1] = n1;
    out[(size_t)8 * NE + ge] = r;
    out[(size_t)9 * NE + ge] = alpha;
  }
}

extern "C" void kernel_launch(void* const* d_in, const int* in_sizes, int n_in,
                              void* d_out, int out_size, void* d_ws, size_t ws_size,
                              hipStream_t stream) {
  const float* node_u = (const float*)d_in[0];
  const float* pn_W1 = (const float*)d_in[6];
  const float* pn_b1 = (const float*)d_in[7];
  const float* pn_W2 = (const float*)d_in[8];
  const float* pn_b2 = (const float*)d_in[9];
  const float* ip_W = (const float*)d_in[10];
  const float* ip_b = (const float*)d_in[11];

  char* ws = (char*)d_ws;
  float* h = (float*)ws;                          // 100000*64*4 = 25,600,000 B
  short* W1P = (short*)(ws + 25600000);           // 81,920 B
  short* W2P = (short*)(ws + 25681920);           // 16,384 B
  short* WHP = (short*)(ws + 25698304);           // 28,672 B
  float* HB = (float*)(ws + 25726976);            // 896 B

  EdgeArgs A;
  A.node_u = node_u;
  A.edge_attr = (const float*)d_in[1];
  A.mean_mom = (const float*)d_in[2];
  A.std_mom = (const float*)d_in[3];
  A.edge_mem = (const float*)d_in[4];
  A.eidx = (const int*)d_in[5];
  A.pe_W1 = (const float*)d_in[12];
  A.pe_b1 = (const float*)d_in[13];
  A.pe_W2 = (const float*)d_in[14];
  A.pe_b2 = (const float*)d_in[15];
  A.pm_b1 = (const float*)d_in[17];
  A.pm_b2 = (const float*)d_in[19];
  A.prho_W2 = (const float*)d_in[22];
  A.prho_b2 = (const float*)d_in[23];
  A.pen_W2 = (const float*)d_in[26];
  A.pen_b2 = (const float*)d_in[27];
  A.pmu_W2 = (const float*)d_in[30];
  A.pmu_b2 = (const float*)d_in[31];
  A.pv_W2 = (const float*)d_in[34];
  A.pv_b2 = (const float*)d_in[35];
  A.ln_g = (const float*)d_in[36];
  A.ln_b = (const float*)d_in[37];
  A.h = h;
  A.W1P = W1P;
  A.W2P = W2P;
  A.WHP = WHP;
  A.HB = HB;
  A.out = (float*)d_out;

  prep_kernel<<<249, 256, 0, stream>>>(
      (const float*)d_in[16], (const float*)d_in[18],
      (const float*)d_in[20], (const float*)d_in[24],
      (const float*)d_in[28], (const float*)d_in[32],
      (const float*)d_in[21], (const float*)d_in[25],
      (const float*)d_in[29], (const float*)d_in[33],
      W1P, W2P, WHP, HB);
  node_h_kernel<<<NN / 4, 256, 0, stream>>>(node_u, pn_W1, pn_b1, pn_W2, pn_b2,
                                            ip_W, ip_b, h);
  edge_kernel<<<NE / 32, 256, 0, stream>>>(A);
}

// Round 3
// 368.542 us; speedup vs baseline: 4.5790x; 1.4121x over previous
//
#include <hip/hip_runtime.h>
#include <math.h>

#define NN 100000
#define NE 500000

typedef short bf16x8 __attribute__((ext_vector_type(8)));
typedef float f32x4 __attribute__((ext_vector_type(4)));

// fast tanh-approx gelu (exp2-based): |err| <= ~3e-3 vs exact erf-gelu.
// Limits are exact: x->+inf => x, x->-inf => 0, x=0 => 0.
__device__ __forceinline__ float gelu_f(float x) {
  const float q = x * fmaf(x * x, 0.044715f, 1.0f);
  const float E = __expf(1.5957691216f * q);       // e^{2*0.7978845608*q}
  const float r = __builtin_amdgcn_rcpf(E + 1.0f); // 1/(E+1)
  return fmaf(-x, r, x);                           // x*(1 - r) = x*0.5*(1+tanh)
}
__device__ __forceinline__ short f2bf(float x) {  // RNE float->bf16
  unsigned u = __builtin_bit_cast(unsigned, x);
  u = (u + 0x7FFFu + ((u >> 16) & 1u)) >> 16;
  return (short)u;
}
__device__ __forceinline__ float bf2f(short s) {
  unsigned u = ((unsigned)(unsigned short)s) << 16;
  return __builtin_bit_cast(float, u);
}
__device__ __forceinline__ float bf2f_lo(unsigned w) {
  return __builtin_bit_cast(float, w << 16);
}
__device__ __forceinline__ float bf2f_hi(unsigned w) {
  return __builtin_bit_cast(float, w & 0xFFFF0000u);
}
__device__ __forceinline__ unsigned pack2(float a, float b) {
  return (unsigned)(unsigned short)f2bf(a) | (((unsigned)(unsigned short)f2bf(b)) << 16);
}

// ---------------- Kernel 1: per-node h = mlp(u,pn) + u@ipW + ipb -> bf16 ----------------
__global__ __launch_bounds__(256) void node_h_kernel(
    const float* __restrict__ node_u,
    const float* __restrict__ W1, const float* __restrict__ b1,
    const float* __restrict__ W2, const float* __restrict__ b2,
    const float* __restrict__ ipW, const float* __restrict__ ipb,
    unsigned short* __restrict__ h) {
  const int lane = threadIdx.x & 63;
  const int node = blockIdx.x * 4 + (threadIdx.x >> 6);
  if (node >= NN) return;
  const float* u = node_u + (size_t)node * 5;
  const float u0 = u[0], u1 = u[1], u2 = u[2], u3 = u[3], u4 = u[4];
  float a = b1[lane];
  a = fmaf(u0, W1[0 * 64 + lane], a);
  a = fmaf(u1, W1[1 * 64 + lane], a);
  a = fmaf(u2, W1[2 * 64 + lane], a);
  a = fmaf(u3, W1[3 * 64 + lane], a);
  a = fmaf(u4, W1[4 * 64 + lane], a);
  const float g = gelu_f(a);
  float acc = b2[lane] + ipb[lane];
  acc = fmaf(u0, ipW[0 * 64 + lane], acc);
  acc = fmaf(u1, ipW[1 * 64 + lane], acc);
  acc = fmaf(u2, ipW[2 * 64 + lane], acc);
  acc = fmaf(u3, ipW[3 * 64 + lane], acc);
  acc = fmaf(u4, ipW[4 * 64 + lane], acc);
  for (int k = 0; k < 64; ++k) {
    acc = fmaf(__shfl(g, k, 64), W2[k * 64 + lane], acc);
  }
  h[(size_t)node * 64 + lane] = (unsigned short)f2bf(acc);
}

// ---------------- Kernel 0: repack GEMM weights to bf16 fragment order ----------------
// Fragment block = 512 bf16: lane l (0..63) x elem e (0..7); value = W[k][n],
// k = ks*32 + 8*(l>>4) + e, n = nt*16 + (l&15).  (A-side uses the same k map.)
__global__ __launch_bounds__(256) void prep_kernel(
    const float* __restrict__ pm_W1, const float* __restrict__ pm_W2,
    const float* __restrict__ prho_W1, const float* __restrict__ pen_W1,
    const float* __restrict__ pmu_W1, const float* __restrict__ pv_W1,
    const float* __restrict__ prho_b1, const float* __restrict__ pen_b1,
    const float* __restrict__ pmu_b1, const float* __restrict__ pv_b1,
    short* __restrict__ W1P, short* __restrict__ W2P, short* __restrict__ WHP,
    float* __restrict__ HB) {
  int t = blockIdx.x * 256 + threadIdx.x;
  if (t < 40960) {  // pm_W1: 292(->320)x128, [nt=8][ks=10][512]
    const int nt = t / 5120, rem = t % 5120;
    const int ks = rem / 512, li = rem % 512;
    const int l = li >> 3, e = li & 7;
    const int k = ks * 32 + ((l >> 4) << 3) + e;
    const int n = nt * 16 + (l & 15);
    W1P[t] = (k < 292) ? f2bf(pm_W1[k * 128 + n]) : (short)0;
    return;
  }
  t -= 40960;
  if (t < 8192) {  // pm_W2: 128x64, [nt=4][ks=4][512]
    const int nt = t / 2048, rem = t % 2048;
    const int ks = rem / 512, li = rem % 512;
    const int l = li >> 3, e = li & 7;
    const int k = ks * 32 + ((l >> 4) << 3) + e;
    const int n = nt * 16 + (l & 15);
    W2P[t] = f2bf(pm_W2[k * 64 + n]);
    return;
  }
  t -= 8192;
  if (t < 14336) {  // heads W1 concat: 64x224, [nt=14][ks=2][512]
    const int nt = t / 1024, rem = t % 1024;
    const int ks = rem / 512, li = rem % 512;
    const int l = li >> 3, e = li & 7;
    const int k = ks * 32 + ((l >> 4) << 3) + e;
    const int col = nt * 16 + (l & 15);
    float v;
    if (col < 64) v = prho_W1[k * 64 + col];
    else if (col < 128) v = pen_W1[k * 64 + (col - 64)];
    else if (col < 192) v = pmu_W1[k * 64 + (col - 128)];
    else v = pv_W1[k * 32 + (col - 192)];
    WHP[t] = f2bf(v);
    return;
  }
  t -= 14336;
  if (t < 224) {  // head biases concat (f32)
    HB[t] = (t < 64) ? prho_b1[t]
          : (t < 128) ? pen_b1[t - 64]
          : (t < 192) ? pmu_b1[t - 128]
          : pv_b1[t - 192];
  }
}

// ---------------- Kernel 2: per-edge fused MFMA pipeline, 32 edges / block ----------------
struct EdgeArgs {
  const float *node_u, *edge_attr, *mean_mom, *std_mom, *edge_mem;
  const int* eidx;
  const float *pe_W1, *pe_b1, *pe_W2, *pe_b2;
  const float *pm_b1, *pm_b2;
  const float *prho_W2, *prho_b2;
  const float *pen_W2, *pen_b2;
  const float *pmu_W2, *pmu_b2;
  const float *pv_W2, *pv_b2;
  const float *ln_g, *ln_b;
  const unsigned short* h;   // bf16
  const short *W1P, *W2P, *WHP;
  const float* HB;
  float* out;
};

#define SMS 328   // msg bf16 row stride (656 B)
#define H1S 136   // h1 bf16 row stride (272 B)
#define MSR 72    // m bf16 row stride (144 B)
#define ZST 233   // z bf16 row stride (466 B)
#define MPS 68    // m_pre f32 row stride

// LDS map (32000 B total -> 5 blocks/CU):
//  [0, 20992): msg bf16 [32][328]          (phase S0*..E2)
//      overlay: m_pre f32 [32][68]  at +0      (E3 -> LN)
//      overlay: aM  bf16 [32][72]   at +15360  (LN -> E4)   [disjoint from mPre & aZ]
//      overlay: aZ  bf16 [32][233]  at +0      (E4 -> E5)
//  [20992, 29696): h1 bf16 [32][136]       (E2 -> E3); early: eps f32 [32][33]
//  [29696, 30720): sSc  f32 [32][8]
//  [30720, 31744): sSc2 f32 [32][8]
//  [31744, 32000): sIdx int [64]
#define OFF_A   0
#define OFF_AM  15360
#define OFF_H1  20992
#define OFF_SC  29696
#define OFF_SC2 30720
#define OFF_IDX 31744
#define SMEM_BYTES 32000

#define MFMA16(a, b, c) __builtin_amdgcn_mfma_f32_16x16x32_bf16((a), (b), (c), 0, 0, 0)

__global__ __launch_bounds__(256, 5) void edge_kernel(EdgeArgs A) {
  __shared__ __align__(16) char smem[SMEM_BYTES];
  short* aA = (short*)(smem + OFF_A);
  short* aH1 = (short*)(smem + OFF_H1);
  float* sEps = (float*)(smem + OFF_H1);
  short* aM = (short*)(smem + OFF_AM);
  float* mPre = (float*)(smem + OFF_A);
  short* aZ = (short*)(smem + OFF_A);
  float* sSc = (float*)(smem + OFF_SC);
  float* sSc2 = (float*)(smem + OFF_SC2);
  int* sIdx = (int*)(smem + OFF_IDX);

  const int tid = threadIdx.x;
  const int e0 = blockIdx.x * 32;
  const int lane = tid & 63;
  const int wv = tid >> 6;
  const int l15 = lane & 15, g = lane >> 4;
  const int mt = wv & 1, nh = wv >> 1;

  // ---- S0a: per-edge scalars (vel_proj, n, t, du, indices) + zero K-pad
  if (tid < 32) {
    const int e = e0 + tid;
    const int s = A.eidx[e];
    const int d = A.eidx[NE + e];
    sIdx[tid] = s;
    sIdx[32 + tid] = d;
    const float dx = A.edge_attr[e * 3 + 0];
    const float dy = A.edge_attr[e * 3 + 1];
    const float r = A.edge_attr[e * 3 + 2];
    const float inv = 1.0f / (r + 1e-12f);
    const float n0 = dx * inv, n1 = dy * inv;  // t = (-n1, n0)
    const float* us = A.node_u + (size_t)s * 5;
    const float* ud = A.node_u + (size_t)d * 5;
    const float sm0 = A.std_mom[0], sm1 = A.std_mom[1];
    const float mm0 = A.mean_mom[0], mm1 = A.mean_mom[1];
    const float rs0 = fmaf(us[3], sm0, mm0), rs1 = fmaf(us[4], sm1, mm1);
    const float rd0 = fmaf(ud[3], sm0, mm0), rd1 = fmaf(ud[4], sm1, mm1);
    const float isc = 1.0f / (sqrtf(sm0 * sm0 + sm1 * sm1) + 1e-8f);
    short* mrow = aA + tid * SMS;
    mrow[288] = f2bf((rs0 * n0 + rs1 * n1) * isc);
    mrow[289] = f2bf((-rs0 * n1 + rs1 * n0) * isc);
    mrow[290] = f2bf((rd0 * n0 + rd1 * n1) * isc);
    mrow[291] = f2bf((-rd0 * n1 + rd1 * n0) * isc);
    unsigned* zp = (unsigned*)(mrow + 292);  // byte offset 584, 4-aligned
#pragma unroll
    for (int z = 0; z < 14; ++z) zp[z] = 0u;  // zero K-pad cols 292..319
    float* st = &sSc[tid * 8];
    st[0] = n0; st[1] = n1; st[2] = r;
    st[3] = ud[0] - us[0];
    st[4] = ud[1] - us[1];
    st[5] = ud[3] - us[3];
    st[6] = ud[4] - us[4];
  }
  __syncthreads();

  // ---- S0b: eps hidden (1 -> 32, gelu), f32 in sEps (overlay on h1 buffer)
  {
    const int i = tid & 31, eg = tid >> 5;
    const float w1 = A.pe_W1[i], b1 = A.pe_b1[i];
#pragma unroll
    for (int p = 0; p < 4; ++p) {
      const int el = eg * 4 + p;
      sEps[el * 33 + i] = gelu_f(fmaf(sSc[el * 8 + 2], w1, b1));
    }
  }
  __syncthreads();

  // ---- S0c: eps out (32 -> 32) -> msg cols [256..288) bf16
  {
    const int i = tid & 31, eg = tid >> 5;
#pragma unroll
    for (int p = 0; p < 4; ++p) {
      const int el = eg * 4 + p;
      float acc = A.pe_b2[i];
      for (int k = 0; k < 32; ++k) acc = fmaf(sEps[el * 33 + k], A.pe_W2[k * 32 + i], acc);
      aA[el * SMS + 256 + i] = f2bf(acc);
    }
  }
  // ---- S0d: h gathers (bf16) -> msg cols [0..256) (raw u32 copies + derived)
  {
    const int c = tid & 31, eg = tid >> 5;
#pragma unroll
    for (int p = 0; p < 4; ++p) {
      const int el = eg * 4 + p;
      const unsigned us_raw = ((const unsigned*)(A.h + (size_t)sIdx[el] * 64))[c];
      const unsigned ud_raw = ((const unsigned*)(A.h + (size_t)sIdx[32 + el] * 64))[c];
      unsigned* rp = (unsigned*)((char*)aA + el * (SMS * 2));
      rp[c] = us_raw;
      rp[32 + c] = ud_raw;
      const float s0 = bf2f_lo(us_raw), s1 = bf2f_hi(us_raw);
      const float d0 = bf2f_lo(ud_raw), d1 = bf2f_hi(ud_raw);
      rp[64 + c] = pack2(s0 + d0, s1 + d1);
      const float q0 = s0 - d0, q1 = s1 - d1;
      rp[96 + c] = pack2(q0 * q0, q1 * q1);
    }
  }
  __syncthreads();

  // ---- E2: layer1 MFMA (K=320 incl pad, N=128). wave (mt,nh): rows 16mt.., cols 64nh..
  {
    const char* arow = (const char*)aA + (mt * 16 + l15) * (SMS * 2) + g * 16;
    const short* BW = A.W1P + nh * 4 * 10 * 512 + lane * 8;
    f32x4 ac0 = {0.f, 0.f, 0.f, 0.f}, ac1 = ac0, ac2 = ac0, ac3 = ac0;
    for (int ks = 0; ks < 10; ++ks) {
      const bf16x8 a = *(const bf16x8*)(arow + ks * 64);
      const bf16x8 b0 = *(const bf16x8*)(BW + (0 * 10 + ks) * 512);
      const bf16x8 b1 = *(const bf16x8*)(BW + (1 * 10 + ks) * 512);
      const bf16x8 b2 = *(const bf16x8*)(BW + (2 * 10 + ks) * 512);
      const bf16x8 b3 = *(const bf16x8*)(BW + (3 * 10 + ks) * 512);
      ac0 = MFMA16(a, b0, ac0);
      ac1 = MFMA16(a, b1, ac1);
      ac2 = MFMA16(a, b2, ac2);
      ac3 = MFMA16(a, b3, ac3);
    }
    const int rb = mt * 16 + g * 4;
#define EPI1(j, accv) { \
    const int col = (nh * 4 + (j)) * 16 + l15; \
    const float bb = A.pm_b1[col]; \
    _Pragma("unroll") \
    for (int rg = 0; rg < 4; ++rg) \
      aH1[(rb + rg) * H1S + col] = f2bf(gelu_f(accv[rg] + bb)); \
  }
    EPI1(0, ac0) EPI1(1, ac1) EPI1(2, ac2) EPI1(3, ac3)
#undef EPI1
  }
  __syncthreads();

  // ---- E3: layer2 MFMA (K=128, N=64) + bias + edge_memory -> m_pre f32 (overlay aA)
  {
    const char* arow = (const char*)aH1 + (mt * 16 + l15) * (H1S * 2) + g * 16;
    const short* BW = A.W2P + nh * 2 * 4 * 512 + lane * 8;
    f32x4 ac0 = {0.f, 0.f, 0.f, 0.f}, ac1 = ac0;
    for (int ks = 0; ks < 4; ++ks) {
      const bf16x8 a = *(const bf16x8*)(arow + ks * 64);
      const bf16x8 b0 = *(const bf16x8*)(BW + (0 * 4 + ks) * 512);
      const bf16x8 b1 = *(const bf16x8*)(BW + (1 * 4 + ks) * 512);
      ac0 = MFMA16(a, b0, ac0);
      ac1 = MFMA16(a, b1, ac1);
    }
    const int rb = mt * 16 + g * 4;
#define EPI2(j, accv) { \
    const int col = (nh * 2 + (j)) * 16 + l15; \
    const float bb = A.pm_b2[col]; \
    _Pragma("unroll") \
    for (int rg = 0; rg < 4; ++rg) { \
      const int row = rb + rg; \
      mPre[row * MPS + col] = accv[rg] + bb + A.edge_mem[(size_t)(e0 + row) * 64 + col]; \
    } \
  }
    EPI2(0, ac0) EPI2(1, ac1)
#undef EPI2
  }
  __syncthreads();

  // ---- LN: shuffle layernorm per edge row; writes m bf16 (aM) + m f32 (global out)
  {
    const float lg = A.ln_g[lane], lb = A.ln_b[lane];
    float* out_m = A.out + (size_t)10 * NE;
#pragma unroll
    for (int p = 0; p < 8; ++p) {
      const int r = p * 4 + wv;
      const float x = mPre[r * MPS + lane];
      float s = x, s2 = x * x;
#pragma unroll
      for (int off = 32; off > 0; off >>= 1) {
        s += __shfl_xor(s, off, 64);
        s2 += __shfl_xor(s2, off, 64);
      }
      const float mean = s * (1.0f / 64.0f);
      const float var = fmaxf(s2 * (1.0f / 64.0f) - mean * mean, 0.0f);
      const float rstd = rsqrtf(var + 1e-5f);
      const float y = fmaf((x - mean) * rstd, lg, lb);
      aM[r * MSR + lane] = f2bf(y);
      out_m[(size_t)(e0 + r) * 64 + lane] = y;
    }
  }
  __syncthreads();

  // ---- E4: head hidden MFMA (K=64, N=224), gelu -> z bf16 (overlay aA[0..14912))
  {
    const char* arow = (const char*)aM + (mt * 16 + l15) * (MSR * 2) + g * 16;
    const bf16x8 a0 = *(const bf16x8*)(arow);
    const bf16x8 a1 = *(const bf16x8*)(arow + 64);
    const short* BW = A.WHP + nh * 7 * 2 * 512 + lane * 8;
    const int rb = mt * 16 + g * 4;
#define HEADJ(j) { \
    f32x4 acc = {0.f, 0.f, 0.f, 0.f}; \
    acc = MFMA16(a0, *(const bf16x8*)(BW + ((j) * 2 + 0) * 512), acc); \
    acc = MFMA16(a1, *(const bf16x8*)(BW + ((j) * 2 + 1) * 512), acc); \
    const int col = (nh * 7 + (j)) * 16 + l15; \
    const float bb = A.HB[col]; \
    _Pragma("unroll") \
    for (int rg = 0; rg < 4; ++rg) \
      aZ[(rb + rg) * ZST + col] = f2bf(gelu_f(acc[rg] + bb)); \
  }
    HEADJ(0) HEADJ(1) HEADJ(2) HEADJ(3) HEADJ(4) HEADJ(5) HEADJ(6)
#undef HEADJ
  }
  __syncthreads();

  // ---- E5: head output dots (thread = edge x head)
  if (tid < 128) {
    const int e = tid & 31, hd = tid >> 5;
    const short* z = aZ + e * ZST;
    if (hd == 0) {
      float a = A.prho_b2[0];
      for (int k = 0; k < 64; ++k) a = fmaf(bf2f(z[k]), A.prho_W2[k], a);
      sSc2[e * 8 + 0] = a;
    } else if (hd == 1) {
      float a = A.pen_b2[0];
      for (int k = 0; k < 64; ++k) a = fmaf(bf2f(z[64 + k]), A.pen_W2[k], a);
      sSc2[e * 8 + 1] = a;
    } else if (hd == 2) {
      float a0 = A.pmu_b2[0], a1 = A.pmu_b2[1];
      for (int k = 0; k < 64; ++k) {
        const float zv = bf2f(z[128 + k]);
        a0 = fmaf(zv, A.pmu_W2[k * 2 + 0], a0);
        a1 = fmaf(zv, A.pmu_W2[k * 2 + 1], a1);
      }
      sSc2[e * 8 + 2] = a0;
      sSc2[e * 8 + 3] = a1;
    } else {
      float a = A.pv_b2[0];
      for (int k = 0; k < 32; ++k) a = fmaf(bf2f(z[192 + k]), A.pv_W2[k], a);
      sSc2[e * 8 + 4] = 1.0f / (1.0f + expf(-a));
    }
  }
  __syncthreads();

  // ---- E5b: flux epilogue
  if (tid < 32) {
    const int e = tid;
    const float* st = &sSc[e * 8];
    const float n0 = st[0], n1 = st[1], r = st[2];
    const float du0 = st[3], du1 = st[4], du3 = st[5], du4 = st[6];
    const float arho = sSc2[e * 8 + 0], aen = sSc2[e * 8 + 1];
    const float amu0 = sSc2[e * 8 + 2], amu1 = sSc2[e * 8 + 3];
    const float alpha = sSc2[e * 8 + 4];
    const size_t ge = (size_t)(e0 + e);
    float* out = A.out;
    const float c0 = arho - alpha * du0;
    out[ge * 2 + 0] = c0 * n0;
    out[ge * 2 + 1] = c0 * n1;
    const float c1 = aen - alpha * du1;
    out[(size_t)2 * NE + ge * 2 + 0] = c1 * n0;
    out[(size_t)2 * NE + ge * 2 + 1] = c1 * n1;
    out[(size_t)4 * NE + ge * 2 + 0] = amu0 * n0 - amu1 * n1 - alpha * du3;
    out[(size_t)4 * NE + ge * 2 + 1] = amu0 * n1 + amu1 * n0 - alpha * du4;
    out[(size_t)6 * NE + ge * 2 + 0] = n0;
    out[(size_t)6 * NE + ge * 2 + 1] = n1;
    out[(size_t)8 * NE + ge] = r;
    out[(size_t)9 * NE + ge] = alpha;
  }
}

extern "C" void kernel_launch(void* const* d_in, const int* in_sizes, int n_in,
                              void* d_out, int out_size, void* d_ws, size_t ws_size,
                              hipStream_t stream) {
  const float* node_u = (const float*)d_in[0];
  const float* pn_W1 = (const float*)d_in[6];
  const float* pn_b1 = (const float*)d_in[7];
  const float* pn_W2 = (const float*)d_in[8];
  const float* pn_b2 = (const float*)d_in[9];
  const float* ip_W = (const float*)d_in[10];
  const float* ip_b = (const float*)d_in[11];

  char* ws = (char*)d_ws;
  unsigned short* h = (unsigned short*)ws;        // 100000*64*2 = 12,800,000 B
  short* W1P = (short*)(ws + 12800000);           // 81,920 B
  short* W2P = (short*)(ws + 12881920);           // 16,384 B
  short* WHP = (short*)(ws + 12898304);           // 28,672 B
  float* HB = (float*)(ws + 12926976);            // 896 B

  EdgeArgs A;
  A.node_u = node_u;
  A.edge_attr = (const float*)d_in[1];
  A.mean_mom = (const float*)d_in[2];
  A.std_mom = (const float*)d_in[3];
  A.edge_mem = (const float*)d_in[4];
  A.eidx = (const int*)d_in[5];
  A.pe_W1 = (const float*)d_in[12];
  A.pe_b1 = (const float*)d_in[13];
  A.pe_W2 = (const float*)d_in[14];
  A.pe_b2 = (const float*)d_in[15];
  A.pm_b1 = (const float*)d_in[17];
  A.pm_b2 = (const float*)d_in[19];
  A.prho_W2 = (const float*)d_in[22];
  A.prho_b2 = (const float*)d_in[23];
  A.pen_W2 = (const float*)d_in[26];
  A.pen_b2 = (const float*)d_in[27];
  A.pmu_W2 = (const float*)d_in[30];
  A.pmu_b2 = (const float*)d_in[31];
  A.pv_W2 = (const float*)d_in[34];
  A.pv_b2 = (const float*)d_in[35];
  A.ln_g = (const float*)d_in[36];
  A.ln_b = (const float*)d_in[37];
  A.h = h;
  A.W1P = W1P;
  A.W2P = W2P;
  A.WHP = WHP;
  A.HB = HB;
  A.out = (float*)d_out;

  prep_kernel<<<249, 256, 0, stream>>>(
      (const float*)d_in[16], (const float*)d_in[18],
      (const float*)d_in[20], (const float*)d_in[24],
      (const float*)d_in[28], (const float*)d_in[32],
      (const float*)d_in[21], (const float*)d_in[25],
      (const float*)d_in[29], (const float*)d_in[33],
      W1P, W2P, WHP, HB);
  node_h_kernel<<<NN / 4, 256, 0, stream>>>(node_u, pn_W1, pn_b1, pn_W2, pn_b2,
                                            ip_W, ip_b, h);
  edge_kernel<<<NE / 32, 256, 0, stream>>>(A);
}

// Round 4
// 284.059 us; speedup vs baseline: 5.9408x; 1.2974x over previous
//
#include <hip/hip_runtime.h>
#include <math.h>

#define NN 100000
#define NE 500000

typedef short bf16x8 __attribute__((ext_vector_type(8)));
typedef float f32x4 __attribute__((ext_vector_type(4)));

// fast tanh-approx gelu (exp2-based): |err| <= ~3e-3 vs exact erf-gelu.
__device__ __forceinline__ float gelu_f(float x) {
  const float q = x * fmaf(x * x, 0.044715f, 1.0f);
  const float E = __builtin_amdgcn_exp2f(2.3022084f * q);  // e^{1.59576912*q}
  const float r = __builtin_amdgcn_rcpf(E + 1.0f);
  return fmaf(-x, r, x);
}
__device__ __forceinline__ short f2bf(float x) {  // RNE float->bf16
  unsigned u = __builtin_bit_cast(unsigned, x);
  u = (u + 0x7FFFu + ((u >> 16) & 1u)) >> 16;
  return (short)u;
}
__device__ __forceinline__ float bf2f(short s) {
  unsigned u = ((unsigned)(unsigned short)s) << 16;
  return __builtin_bit_cast(float, u);
}
__device__ __forceinline__ float bf2f_lo(unsigned w) {
  return __builtin_bit_cast(float, w << 16);
}
__device__ __forceinline__ float bf2f_hi(unsigned w) {
  return __builtin_bit_cast(float, w & 0xFFFF0000u);
}
__device__ __forceinline__ unsigned pack2(float a, float b) {
  return (unsigned)(unsigned short)f2bf(a) | (((unsigned)(unsigned short)f2bf(b)) << 16);
}

// ---------------- Kernel 1: per-node h = mlp(u,pn) + u@ipW + ipb -> bf16 ----------------
__global__ __launch_bounds__(256) void node_h_kernel(
    const float* __restrict__ node_u,
    const float* __restrict__ W1, const float* __restrict__ b1,
    const float* __restrict__ W2, const float* __restrict__ b2,
    const float* __restrict__ ipW, const float* __restrict__ ipb,
    unsigned short* __restrict__ h) {
  const int lane = threadIdx.x & 63;
  const int node = blockIdx.x * 4 + (threadIdx.x >> 6);
  if (node >= NN) return;
  const float* u = node_u + (size_t)node * 5;
  const float u0 = u[0], u1 = u[1], u2 = u[2], u3 = u[3], u4 = u[4];
  float a = b1[lane];
  a = fmaf(u0, W1[0 * 64 + lane], a);
  a = fmaf(u1, W1[1 * 64 + lane], a);
  a = fmaf(u2, W1[2 * 64 + lane], a);
  a = fmaf(u3, W1[3 * 64 + lane], a);
  a = fmaf(u4, W1[4 * 64 + lane], a);
  const float g = gelu_f(a);
  float acc = b2[lane] + ipb[lane];
  acc = fmaf(u0, ipW[0 * 64 + lane], acc);
  acc = fmaf(u1, ipW[1 * 64 + lane], acc);
  acc = fmaf(u2, ipW[2 * 64 + lane], acc);
  acc = fmaf(u3, ipW[3 * 64 + lane], acc);
  acc = fmaf(u4, ipW[4 * 64 + lane], acc);
  for (int k = 0; k < 64; ++k) {
    acc = fmaf(__shfl(g, k, 64), W2[k * 64 + lane], acc);
  }
  h[(size_t)node * 64 + lane] = (unsigned short)f2bf(acc);
}

// ---------------- Kernel 0: repack GEMM weights to bf16 fragment order ----------------
// Fragment block = 512 bf16: lane l (0..63) x elem e (0..7); value = W[k][n],
// k = ks*32 + 8*(l>>4) + e, n = nt*16 + (l&15).  (A-side uses the same k map.)
__global__ __launch_bounds__(256) void prep_kernel(
    const float* __restrict__ pm_W1, const float* __restrict__ pm_W2,
    const float* __restrict__ prho_W1, const float* __restrict__ pen_W1,
    const float* __restrict__ pmu_W1, const float* __restrict__ pv_W1,
    const float* __restrict__ prho_b1, const float* __restrict__ pen_b1,
    const float* __restrict__ pmu_b1, const float* __restrict__ pv_b1,
    const float* __restrict__ pe_W2,
    const float* __restrict__ prho_W2, const float* __restrict__ pen_W2,
    const float* __restrict__ pmu_W2, const float* __restrict__ pv_W2,
    const float* __restrict__ prho_b2, const float* __restrict__ pen_b2,
    const float* __restrict__ pmu_b2, const float* __restrict__ pv_b2,
    short* __restrict__ W1P, short* __restrict__ W2P, short* __restrict__ WHP,
    float* __restrict__ HB, short* __restrict__ WEP, short* __restrict__ WOP,
    float* __restrict__ HB2) {
  int t = blockIdx.x * 256 + threadIdx.x;
  if (t < 40960) {  // pm_W1: 292(->320)x128, [nt=8][ks=10][512]
    const int nt = t / 5120, rem = t % 5120;
    const int ks = rem / 512, li = rem % 512;
    const int l = li >> 3, e = li & 7;
    const int k = ks * 32 + ((l >> 4) << 3) + e;
    const int n = nt * 16 + (l & 15);
    W1P[t] = (k < 292) ? f2bf(pm_W1[k * 128 + n]) : (short)0;
    return;
  }
  t -= 40960;
  if (t < 8192) {  // pm_W2: 128x64, [nt=4][ks=4][512]
    const int nt = t / 2048, rem = t % 2048;
    const int ks = rem / 512, li = rem % 512;
    const int l = li >> 3, e = li & 7;
    const int k = ks * 32 + ((l >> 4) << 3) + e;
    const int n = nt * 16 + (l & 15);
    W2P[t] = f2bf(pm_W2[k * 64 + n]);
    return;
  }
  t -= 8192;
  if (t < 14336) {  // heads W1 concat: 64x224, [nt=14][ks=2][512]
    const int nt = t / 1024, rem = t % 1024;
    const int ks = rem / 512, li = rem % 512;
    const int l = li >> 3, e = li & 7;
    const int k = ks * 32 + ((l >> 4) << 3) + e;
    const int col = nt * 16 + (l & 15);
    float v;
    if (col < 64) v = prho_W1[k * 64 + col];
    else if (col < 128) v = pen_W1[k * 64 + (col - 64)];
    else if (col < 192) v = pmu_W1[k * 64 + (col - 128)];
    else v = pv_W1[k * 32 + (col - 192)];
    WHP[t] = f2bf(v);
    return;
  }
  t -= 14336;
  if (t < 224) {  // head hidden biases concat (f32)
    HB[t] = (t < 64) ? prho_b1[t]
          : (t < 128) ? pen_b1[t - 64]
          : (t < 192) ? pmu_b1[t - 128]
          : pv_b1[t - 192];
    return;
  }
  t -= 224;
  if (t < 1024) {  // pe_W2: 32x32, [nt=2][512]
    const int nt = t / 512, li = t % 512;
    const int l = li >> 3, e = li & 7;
    const int k = ((l >> 4) << 3) + e;
    const int n = nt * 16 + (l & 15);
    WEP[t] = f2bf(pe_W2[k * 32 + n]);
    return;
  }
  t -= 1024;
  if (t < 3584) {  // stacked head W2: 224x16, [ks=7][512]
    const int ks = t / 512, li = t % 512;
    const int l = li >> 3, e = li & 7;
    const int k = ks * 32 + ((l >> 4) << 3) + e;
    const int j = l & 15;
    float v = 0.0f;
    if (j == 0 && k < 64) v = prho_W2[k];
    else if (j == 1 && k >= 64 && k < 128) v = pen_W2[k - 64];
    else if (j == 2 && k >= 128 && k < 192) v = pmu_W2[(k - 128) * 2 + 0];
    else if (j == 3 && k >= 128 && k < 192) v = pmu_W2[(k - 128) * 2 + 1];
    else if (j == 4 && k >= 192 && k < 224) v = pv_W2[k - 192];
    WOP[t] = f2bf(v);
    return;
  }
  t -= 3584;
  if (t < 16) {  // head output biases
    HB2[t] = (t == 0) ? prho_b2[0]
           : (t == 1) ? pen_b2[0]
           : (t == 2) ? pmu_b2[0]
           : (t == 3) ? pmu_b2[1]
           : (t == 4) ? pv_b2[0] : 0.0f;
  }
}

// ---------------- Kernel 2: per-edge fused MFMA pipeline, 32 edges / block ----------------
struct EdgeArgs {
  const float *node_u, *edge_attr, *mean_mom, *std_mom, *edge_mem;
  const int* eidx;
  const float *pe_W1, *pe_b1, *pe_b2;
  const float *pm_b1, *pm_b2;
  const float *ln_g, *ln_b;
  const unsigned short* h;   // bf16
  const short *W1P, *W2P, *WHP, *WEP, *WOP;
  const float *HB, *HB2;
  float* out;
};

#define SMS 328   // msg bf16 row stride (656 B)
#define H1S 136   // h1 bf16 row stride (272 B)
#define MSR 72    // m bf16 row stride (144 B)
#define ZST 240   // z bf16 row stride (480 B, 16B-aligned)
#define EPS 40    // eps-hidden bf16 row stride (80 B)

// LDS map (32000 B -> 5 blocks/CU):
//  [0, 20992): msg bf16 [32][328]              (S0*..E2)
//      overlay: aMq bf16 [32][72] @ +8704      (E3 -> LNsums)
//      overlay: aZ  bf16 [32][240] @ +0        (E4 -> E5), ends 15360
//  [15360, 19968): aMp/aM bf16 [32][72]        (E3 -> E4; in-place LN)
//  [20992, 29696): h1 bf16 [32][136]           (E2 -> E3); early: epsB bf16 [32][40]
//  [29696, 30720): sSc  f32 [32][8]
//  [30720, 31744): sSc2 f32 [32][8]
//  [31744, 32000): sIdx int[64] (early) / sSums f32[64] (LN)
#define OFF_A   0
#define OFF_MQ  8704
#define OFF_AM  15360
#define OFF_H1  20992
#define OFF_SC  29696
#define OFF_SC2 30720
#define OFF_IDX 31744
#define SMEM_BYTES 32000

#define MFMA16(a, b, c) __builtin_amdgcn_mfma_f32_16x16x32_bf16((a), (b), (c), 0, 0, 0)

__global__ __launch_bounds__(256, 5) void edge_kernel(EdgeArgs A) {
  __shared__ __align__(16) char smem[SMEM_BYTES];
  short* aA = (short*)(smem + OFF_A);
  short* aMq = (short*)(smem + OFF_MQ);
  short* aM = (short*)(smem + OFF_AM);
  short* aZ = (short*)(smem + OFF_A);
  short* aH1 = (short*)(smem + OFF_H1);
  short* epsB = (short*)(smem + OFF_H1);
  float* sSc = (float*)(smem + OFF_SC);
  float* sSc2 = (float*)(smem + OFF_SC2);
  int* sIdx = (int*)(smem + OFF_IDX);
  float* sSums = (float*)(smem + OFF_IDX);

  const int tid = threadIdx.x;
  const int e0 = blockIdx.x * 32;
  const int lane = tid & 63;
  const int wv = tid >> 6;
  const int l15 = lane & 15, g = lane >> 4;
  const int mt = wv & 1, nh = wv >> 1;

  // ---- S0a: per-edge scalars (vel_proj, n, t, du, indices) + zero K-pad
  if (tid < 32) {
    const int e = e0 + tid;
    const int s = A.eidx[e];
    const int d = A.eidx[NE + e];
    sIdx[tid] = s;
    sIdx[32 + tid] = d;
    const float dx = A.edge_attr[e * 3 + 0];
    const float dy = A.edge_attr[e * 3 + 1];
    const float r = A.edge_attr[e * 3 + 2];
    const float inv = 1.0f / (r + 1e-12f);
    const float n0 = dx * inv, n1 = dy * inv;  // t = (-n1, n0)
    const float* us = A.node_u + (size_t)s * 5;
    const float* ud = A.node_u + (size_t)d * 5;
    const float sm0 = A.std_mom[0], sm1 = A.std_mom[1];
    const float mm0 = A.mean_mom[0], mm1 = A.mean_mom[1];
    const float rs0 = fmaf(us[3], sm0, mm0), rs1 = fmaf(us[4], sm1, mm1);
    const float rd0 = fmaf(ud[3], sm0, mm0), rd1 = fmaf(ud[4], sm1, mm1);
    const float isc = 1.0f / (sqrtf(sm0 * sm0 + sm1 * sm1) + 1e-8f);
    short* mrow = aA + tid * SMS;
    mrow[288] = f2bf((rs0 * n0 + rs1 * n1) * isc);
    mrow[289] = f2bf((-rs0 * n1 + rs1 * n0) * isc);
    mrow[290] = f2bf((rd0 * n0 + rd1 * n1) * isc);
    mrow[291] = f2bf((-rd0 * n1 + rd1 * n0) * isc);
    unsigned* zp = (unsigned*)(mrow + 292);
#pragma unroll
    for (int z = 0; z < 14; ++z) zp[z] = 0u;  // zero K-pad cols 292..319
    float* st = &sSc[tid * 8];
    st[0] = n0; st[1] = n1; st[2] = r;
    st[3] = ud[0] - us[0];
    st[4] = ud[1] - us[1];
    st[5] = ud[3] - us[3];
    st[6] = ud[4] - us[4];
  }
  __syncthreads();

  // ---- S0b: eps hidden (1 -> 32, gelu) -> epsB bf16 [32][40]
  {
    const int i = tid & 31, eg = tid >> 5;
    const float w1 = A.pe_W1[i], b1 = A.pe_b1[i];
#pragma unroll
    for (int p = 0; p < 4; ++p) {
      const int el = eg * 4 + p;
      epsB[el * EPS + i] = f2bf(gelu_f(fmaf(sSc[el * 8 + 2], w1, b1)));
    }
  }
  __syncthreads();

  // ---- S0c: eps out via MFMA (M=32,K=32,N=32) -> msg cols [256..288)
  {
    const bf16x8 a = *(const bf16x8*)((const char*)epsB + (mt * 16 + l15) * (EPS * 2) + g * 16);
    const bf16x8 b = *(const bf16x8*)(A.WEP + nh * 512 + lane * 8);
    f32x4 acc = {0.f, 0.f, 0.f, 0.f};
    acc = MFMA16(a, b, acc);
    const int col = 256 + nh * 16 + l15;
    const float bb = A.pe_b2[nh * 16 + l15];
#pragma unroll
    for (int rg = 0; rg < 4; ++rg)
      aA[(mt * 16 + g * 4 + rg) * SMS + col] = f2bf(acc[rg] + bb);
  }
  // ---- S0d: h gathers (bf16) -> msg cols [0..256)
  {
    const int c = tid & 31, eg = tid >> 5;
#pragma unroll
    for (int p = 0; p < 4; ++p) {
      const int el = eg * 4 + p;
      const unsigned us_raw = ((const unsigned*)(A.h + (size_t)sIdx[el] * 64))[c];
      const unsigned ud_raw = ((const unsigned*)(A.h + (size_t)sIdx[32 + el] * 64))[c];
      unsigned* rp = (unsigned*)((char*)aA + el * (SMS * 2));
      rp[c] = us_raw;
      rp[32 + c] = ud_raw;
      const float s0 = bf2f_lo(us_raw), s1 = bf2f_hi(us_raw);
      const float d0 = bf2f_lo(ud_raw), d1 = bf2f_hi(ud_raw);
      rp[64 + c] = pack2(s0 + d0, s1 + d1);
      const float q0 = s0 - d0, q1 = s1 - d1;
      rp[96 + c] = pack2(q0 * q0, q1 * q1);
    }
  }
  __syncthreads();

  // ---- E2: layer1 MFMA (K=320 incl pad, N=128)
  {
    const char* arow = (const char*)aA + (mt * 16 + l15) * (SMS * 2) + g * 16;
    const short* BW = A.W1P + nh * 4 * 10 * 512 + lane * 8;
    f32x4 ac0 = {0.f, 0.f, 0.f, 0.f}, ac1 = ac0, ac2 = ac0, ac3 = ac0;
    for (int ks = 0; ks < 10; ++ks) {
      const bf16x8 a = *(const bf16x8*)(arow + ks * 64);
      const bf16x8 b0 = *(const bf16x8*)(BW + (0 * 10 + ks) * 512);
      const bf16x8 b1 = *(const bf16x8*)(BW + (1 * 10 + ks) * 512);
      const bf16x8 b2 = *(const bf16x8*)(BW + (2 * 10 + ks) * 512);
      const bf16x8 b3 = *(const bf16x8*)(BW + (3 * 10 + ks) * 512);
      ac0 = MFMA16(a, b0, ac0);
      ac1 = MFMA16(a, b1, ac1);
      ac2 = MFMA16(a, b2, ac2);
      ac3 = MFMA16(a, b3, ac3);
    }
    const int rb = mt * 16 + g * 4;
#define EPI1(j, accv) { \
    const int col = (nh * 4 + (j)) * 16 + l15; \
    const float bb = A.pm_b1[col]; \
    _Pragma("unroll") \
    for (int rg = 0; rg < 4; ++rg) \
      aH1[(rb + rg) * H1S + col] = f2bf(gelu_f(accv[rg] + bb)); \
  }
    EPI1(0, ac0) EPI1(1, ac1) EPI1(2, ac2) EPI1(3, ac3)
#undef EPI1
  }
  __syncthreads();

  // ---- E3: layer2 MFMA (K=128, N=64) + bias + edge_memory -> aM (x) + aMq (x^2) bf16
  {
    const char* arow = (const char*)aH1 + (mt * 16 + l15) * (H1S * 2) + g * 16;
    const short* BW = A.W2P + nh * 2 * 4 * 512 + lane * 8;
    f32x4 ac0 = {0.f, 0.f, 0.f, 0.f}, ac1 = ac0;
    for (int ks = 0; ks < 4; ++ks) {
      const bf16x8 a = *(const bf16x8*)(arow + ks * 64);
      const bf16x8 b0 = *(const bf16x8*)(BW + (0 * 4 + ks) * 512);
      const bf16x8 b1 = *(const bf16x8*)(BW + (1 * 4 + ks) * 512);
      ac0 = MFMA16(a, b0, ac0);
      ac1 = MFMA16(a, b1, ac1);
    }
    const int rb = mt * 16 + g * 4;
#define EPI2(j, accv) { \
    const int col = (nh * 2 + (j)) * 16 + l15; \
    const float bb = A.pm_b2[col]; \
    _Pragma("unroll") \
    for (int rg = 0; rg < 4; ++rg) { \
      const int row = rb + rg; \
      const float x = accv[rg] + bb + A.edge_mem[(size_t)(e0 + row) * 64 + col]; \
      aM[row * MSR + col] = f2bf(x); \
      aMq[row * MSR + col] = f2bf(x * x); \
    } \
  }
    EPI2(0, ac0) EPI2(1, ac1)
#undef EPI2
  }
  __syncthreads();

  // ---- LN sums via MFMA: wave (mt, q): C = A . ones, rows mt*16.., A = x or x^2
  {
    const int q = wv >> 1;
    const short* src = q ? aMq : aM;
    const short ONE = (short)0x3F80;
    const bf16x8 bones = {ONE, ONE, ONE, ONE, ONE, ONE, ONE, ONE};
    f32x4 acc = {0.f, 0.f, 0.f, 0.f};
#pragma unroll
    for (int ks = 0; ks < 2; ++ks) {
      const bf16x8 a = *(const bf16x8*)((const char*)src + (mt * 16 + l15) * (MSR * 2) + ks * 64 + g * 16);
      acc = MFMA16(a, bones, acc);
    }
    if (l15 == 0) {
#pragma unroll
      for (int rg = 0; rg < 4; ++rg)
        sSums[q * 32 + mt * 16 + g * 4 + rg] = acc[rg];
    }
  }
  __syncthreads();

  // ---- LN normalize (elementwise, in-place on aM) + m f32 output
  {
    const float lg = A.ln_g[lane], lb = A.ln_b[lane];
    float* out_m = A.out + (size_t)10 * NE;
#pragma unroll
    for (int p = 0; p < 8; ++p) {
      const int r = p * 4 + wv;
      const float x = bf2f(aM[r * MSR + lane]);
      const float mean = sSums[r] * (1.0f / 64.0f);
      const float var = fmaxf(sSums[32 + r] * (1.0f / 64.0f) - mean * mean, 0.0f);
      const float rstd = rsqrtf(var + 1e-5f);
      const float y = fmaf((x - mean) * rstd, lg, lb);
      aM[r * MSR + lane] = f2bf(y);
      out_m[(size_t)(e0 + r) * 64 + lane] = y;
    }
  }
  __syncthreads();

  // ---- E4: head hidden MFMA (K=64, N=224), gelu -> z bf16 (stride 240, overlay aA)
  {
    const char* arow = (const char*)aM + (mt * 16 + l15) * (MSR * 2) + g * 16;
    const bf16x8 a0 = *(const bf16x8*)(arow);
    const bf16x8 a1 = *(const bf16x8*)(arow + 64);
    const short* BW = A.WHP + nh * 7 * 2 * 512 + lane * 8;
    const int rb = mt * 16 + g * 4;
#define HEADJ(j) { \
    f32x4 acc = {0.f, 0.f, 0.f, 0.f}; \
    acc = MFMA16(a0, *(const bf16x8*)(BW + ((j) * 2 + 0) * 512), acc); \
    acc = MFMA16(a1, *(const bf16x8*)(BW + ((j) * 2 + 1) * 512), acc); \
    const int col = (nh * 7 + (j)) * 16 + l15; \
    const float bb = A.HB[col]; \
    _Pragma("unroll") \
    for (int rg = 0; rg < 4; ++rg) \
      aZ[(rb + rg) * ZST + col] = f2bf(gelu_f(acc[rg] + bb)); \
  }
    HEADJ(0) HEADJ(1) HEADJ(2) HEADJ(3) HEADJ(4) HEADJ(5) HEADJ(6)
#undef HEADJ
  }
  __syncthreads();

  // ---- E5: head outputs via MFMA (M=32, K=224, N=16; cols 0..4 valid)
  if (wv < 2) {
    f32x4 acc = {0.f, 0.f, 0.f, 0.f};
    for (int ks = 0; ks < 7; ++ks) {
      const bf16x8 a = *(const bf16x8*)((const char*)aZ + (wv * 16 + l15) * (ZST * 2) + ks * 64 + g * 16);
      const bf16x8 b = *(const bf16x8*)(A.WOP + ks * 512 + lane * 8);
      acc = MFMA16(a, b, acc);
    }
    if (l15 < 5) {
      const float bb = A.HB2[l15];
#pragma unroll
      for (int rg = 0; rg < 4; ++rg)
        sSc2[(wv * 16 + g * 4 + rg) * 8 + l15] = acc[rg] + bb;
    }
  }
  __syncthreads();

  // ---- E5b: flux epilogue
  if (tid < 32) {
    const int e = tid;
    const float* st = &sSc[e * 8];
    const float n0 = st[0], n1 = st[1], r = st[2];
    const float du0 = st[3], du1 = st[4], du3 = st[5], du4 = st[6];
    const float arho = sSc2[e * 8 + 0], aen = sSc2[e * 8 + 1];
    const float amu0 = sSc2[e * 8 + 2], amu1 = sSc2[e * 8 + 3];
    const float av = sSc2[e * 8 + 4];
    const float alpha = __builtin_amdgcn_rcpf(1.0f + __builtin_amdgcn_exp2f(-1.4426950408f * av));
    const size_t ge = (size_t)(e0 + e);
    float* out = A.out;
    const float c0 = arho - alpha * du0;
    out[ge * 2 + 0] = c0 * n0;
    out[ge * 2 + 1] = c0 * n1;
    const float c1 = aen - alpha * du1;
    out[(size_t)2 * NE + ge * 2 + 0] = c1 * n0;
    out[(size_t)2 * NE + ge * 2 + 1] = c1 * n1;
    out[(size_t)4 * NE + ge * 2 + 0] = amu0 * n0 - amu1 * n1 - alpha * du3;
    out[(size_t)4 * NE + ge * 2 + 1] = amu0 * n1 + amu1 * n0 - alpha * du4;
    out[(size_t)6 * NE + ge * 2 + 0] = n0;
    out[(size_t)6 * NE + ge * 2 + 1] = n1;
    out[(size_t)8 * NE + ge] = r;
    out[(size_t)9 * NE + ge] = alpha;
  }
}

extern "C" void kernel_launch(void* const* d_in, const int* in_sizes, int n_in,
                              void* d_out, int out_size, void* d_ws, size_t ws_size,
                              hipStream_t stream) {
  const float* node_u = (const float*)d_in[0];
  const float* pn_W1 = (const float*)d_in[6];
  const float* pn_b1 = (const float*)d_in[7];
  const float* pn_W2 = (const float*)d_in[8];
  const float* pn_b2 = (const float*)d_in[9];
  const float* ip_W = (const float*)d_in[10];
  const float* ip_b = (const float*)d_in[11];

  char* ws = (char*)d_ws;
  unsigned short* h = (unsigned short*)ws;        // 12,800,000 B
  short* W1P = (short*)(ws + 12800000);           // 81,920 B
  short* W2P = (short*)(ws + 12881920);           // 16,384 B
  short* WHP = (short*)(ws + 12898304);           // 28,672 B
  float* HB  = (float*)(ws + 12926976);           // 896 B
  short* WEP = (short*)(ws + 12927872);           // 2,048 B
  short* WOP = (short*)(ws + 12929920);           // 7,168 B
  float* HB2 = (float*)(ws + 12937088);           // 64 B

  EdgeArgs A;
  A.node_u = node_u;
  A.edge_attr = (const float*)d_in[1];
  A.mean_mom = (const float*)d_in[2];
  A.std_mom = (const float*)d_in[3];
  A.edge_mem = (const float*)d_in[4];
  A.eidx = (const int*)d_in[5];
  A.pe_W1 = (const float*)d_in[12];
  A.pe_b1 = (const float*)d_in[13];
  A.pe_b2 = (const float*)d_in[15];
  A.pm_b1 = (const float*)d_in[17];
  A.pm_b2 = (const float*)d_in[19];
  A.ln_g = (const float*)d_in[36];
  A.ln_b = (const float*)d_in[37];
  A.h = h;
  A.W1P = W1P;
  A.W2P = W2P;
  A.WHP = WHP;
  A.WEP = WEP;
  A.WOP = WOP;
  A.HB = HB;
  A.HB2 = HB2;
  A.out = (float*)d_out;

  prep_kernel<<<267, 256, 0, stream>>>(
      (const float*)d_in[16], (const float*)d_in[18],
      (const float*)d_in[20], (const float*)d_in[24],
      (const float*)d_in[28], (const float*)d_in[32],
      (const float*)d_in[21], (const float*)d_in[25],
      (const float*)d_in[29], (const float*)d_in[33],
      (const float*)d_in[14],
      (const float*)d_in[22], (const float*)d_in[26],
      (const float*)d_in[30], (const float*)d_in[34],
      (const float*)d_in[23], (const float*)d_in[27],
      (const float*)d_in[31], (const float*)d_in[35],
      W1P, W2P, WHP, HB, WEP, WOP, HB2);
  node_h_kernel<<<NN / 4, 256, 0, stream>>>(node_u, pn_W1, pn_b1, pn_W2, pn_b2,
                                            ip_W, ip_b, h);
  edge_kernel<<<NE / 32, 256, 0, stream>>>(A);
}